// Round 2
// baseline (895.461 us; speedup 1.0000x reference)
//
#include <hip/hip_runtime.h>
#include <hip/hip_cooperative_groups.h>
#include <hip/hip_bf16.h>
#include <math.h>

namespace cg = cooperative_groups;

#define HF 128          // hidden / input feature dim
#define GCOUNT 64       // graphs in batch
#define OUTF 64         // final output features
#define NEG 0.2f        // leaky relu slope
#define CH 2048         // edges per partition block
#define BCAP 8192       // per-bucket edge capacity (expected ~4340, +50 sigma)
#define PROWS 32        // rows per pooling block (fallback path)

typedef unsigned short u16;
typedef unsigned int   u32;
typedef unsigned char  u8;
typedef short bf16x8 __attribute__((ext_vector_type(8)));
typedef float f32x4  __attribute__((ext_vector_type(4)));
typedef float f32x2  __attribute__((ext_vector_type(2)));

// fp32 -> bf16 (RNE) bit trick
__device__ __forceinline__ u16 f2b(float f) {
    u32 u = __builtin_bit_cast(u32, f);
    u32 r = (u + 0x7FFFu + ((u >> 16) & 1u)) >> 16;
    return (u16)r;
}

// ---- hardware fp8 e4m3fn codec (gfx950 OCP; v_cvt_pk_* — 2 elems/inst) ----
__device__ __forceinline__ u8 f2q(float f) {
    return (u8)(__builtin_amdgcn_cvt_pk_fp8_f32(f, f, 0, false) & 0xFF);
}

// ======================= device stage functions =======================

// item w in [0,65): 0..31 pack weights, 32 init bucketCur, 33..64 zero pooled
__device__ __forceinline__ void dev_pack_init(int w, const float* __restrict__ W0,
                                              const float* __restrict__ Wl,
                                              u16* __restrict__ P, int* bucketCur,
                                              float* pooled) {
    if (w < 32) {
        int m = w >> 3;                       // 0..3: W0, Wl[0..2]
        int i = (w & 7) * 256 + threadIdx.x;  // 0..2047
        const float* W = (m == 0) ? W0 : Wl + (size_t)(m - 1) * HF * HF;
        u16* Pm = P + (size_t)m * HF * HF;
        int lane = i & 63, kc = (i >> 6) & 3, t = i >> 8;
        int quad = lane >> 4, col = 16 * t + (lane & 15);
        #pragma unroll
        for (int j = 0; j < 8; ++j) {
            int k = kc * 32 + quad * 8 + j;
            Pm[(size_t)i * 8 + j] = f2b(W[k * HF + col]);
        }
    } else if (w == 32) {
        bucketCur[threadIdx.x] = threadIdx.x * BCAP;
    } else {
        pooled[(w - 33) * 256 + threadIdx.x] = 0.f;
    }
}

// bucketed partition: LDS hist -> chunk reservation -> packed scatter (src<<8|dst&255)
__device__ __forceinline__ void dev_bpart(int bx, const int* __restrict__ esrc,
                                          const int* __restrict__ edst,
                                          int* __restrict__ bucketCur,
                                          u32* __restrict__ epart, int ne, int ntot) {
    __shared__ int cnt[256];
    __shared__ int base[256];
    int tid = threadIdx.x;
    int t0 = bx * CH, t1 = min(t0 + CH, ntot);
    cnt[tid] = 0;
    __syncthreads();
    int sreg[8], dreg[8];
    #pragma unroll
    for (int it = 0; it < 8; ++it) {
        int t = t0 + tid + it * 256;
        int s = 0, d = -1;
        if (t < t1) {
            if (t < ne) { s = esrc[t]; d = edst[t]; }
            else        { s = t - ne; d = s; }
            atomicAdd(&cnt[d >> 8], 1);
        }
        sreg[it] = s; dreg[it] = d;
    }
    __syncthreads();
    int c = cnt[tid];
    base[tid] = c ? atomicAdd(&bucketCur[tid], c) : 0;
    cnt[tid] = 0;
    __syncthreads();
    #pragma unroll
    for (int it = 0; it < 8; ++it) {
        int d = dreg[it];
        if (d >= 0) {
            int b = d >> 8;
            int pos = base[b] + atomicAdd(&cnt[b], 1);
            epart[pos] = ((u32)sreg[it] << 8) | (u32)(d & 255);
        }
    }
}

// per-bucket: degree hist + scan -> rowbeg/rowend + colidx scatter
__device__ __forceinline__ void dev_bcsr(int bx, const u32* __restrict__ epart,
                                         const int* __restrict__ bucketCur,
                                         int* __restrict__ rowbeg,
                                         int* __restrict__ rowend,
                                         int* __restrict__ colidx, int n) {
    __shared__ int deg[256], offs[256], curs[256], s[256];
    int b = bx, tid = threadIdx.x;
    int e0 = b * BCAP, e1 = bucketCur[b];
    deg[tid] = 0;
    curs[tid] = 0;
    __syncthreads();
    for (int t = e0 + tid; t < e1; t += 256)
        atomicAdd(&deg[epart[t] & 255u], 1);
    __syncthreads();
    int v = deg[tid];
    s[tid] = v;
    __syncthreads();
    int acc = v;
    for (int off = 1; off < 256; off <<= 1) {
        int t = (tid >= off) ? s[tid - off] : 0;
        __syncthreads();
        acc += t;
        s[tid] = acc;
        __syncthreads();
    }
    int excl = acc - v;
    offs[tid] = excl;
    int node = (b << 8) + tid;
    if (node < n) {
        rowbeg[node] = e0 + excl;
        rowend[node] = e0 + excl + v;
    }
    __syncthreads();
    for (int t = e0 + tid; t < e1; t += 256) {
        u32 e = epart[t];
        int l = e & 255u;
        int pos = e0 + offs[l] + atomicAdd(&curs[l], 1);
        colidx[pos] = (int)(e >> 8);
    }
}

// MFMA GEMM (+bias, + optional fused alpha dots)
// block = 256 (4 waves); wave w owns rows m0+16w..+15, all 128 cols (8 n-tiles).
template<bool A32, bool Q8>
__device__ __forceinline__ void dev_gemm(int bx, const u16* __restrict__ Ab,
                                         const float* __restrict__ Af,
                                         const u16* __restrict__ Bp,
                                         const float* __restrict__ bias,
                                         const float* __restrict__ a_s,
                                         const float* __restrict__ a_d,
                                         float* __restrict__ as_,
                                         float* __restrict__ ad_,
                                         u16* __restrict__ C,
                                         u8* __restrict__ C8, int M) {
    int lane = threadIdx.x & 63;
    int wave = threadIdx.x >> 6;
    int quad = lane >> 4, l16 = lane & 15;
    int m0 = bx * 64 + wave * 16;
    int arow = m0 + l16;
    bool aval = arow < M;
    const bf16x8* Av = A32 ? nullptr : (const bf16x8*)(Ab + (size_t)arow * HF);
    const bf16x8* Bv = (const bf16x8*)Bp;
    f32x4 acc[8] = {};

    #pragma unroll
    for (int kc = 0; kc < 4; ++kc) {
        bf16x8 a = {};
        if (aval) {
            if constexpr (A32) {
                const float* ap = Af + (size_t)arow * HF + kc * 32 + quad * 8;
                float4 f0 = *(const float4*)ap;
                float4 f1 = *(const float4*)(ap + 4);
                a[0] = (short)f2b(f0.x); a[1] = (short)f2b(f0.y);
                a[2] = (short)f2b(f0.z); a[3] = (short)f2b(f0.w);
                a[4] = (short)f2b(f1.x); a[5] = (short)f2b(f1.y);
                a[6] = (short)f2b(f1.z); a[7] = (short)f2b(f1.w);
            } else {
                a = Av[kc * 4 + quad];
            }
        }
        #pragma unroll
        for (int t = 0; t < 8; ++t)
            acc[t] = __builtin_amdgcn_mfma_f32_16x16x32_bf16(a, Bv[t * 256 + kc * 64 + lane],
                                                             acc[t], 0, 0, 0);
    }

    int orow0 = m0 + quad * 4;
    #pragma unroll
    for (int t = 0; t < 8; ++t) {
        float b4 = bias ? bias[t * 16 + l16] : 0.f;
        #pragma unroll
        for (int r = 0; r < 4; ++r) {
            int orow = orow0 + r;
            if (orow < M) {
                float v = acc[t][r] + b4;
                if constexpr (Q8) C8[(size_t)orow * HF + t * 16 + l16] = f2q(v);
                else              C [(size_t)orow * HF + t * 16 + l16] = f2b(v);
            }
        }
    }

    if (as_) {
        float avs[8], avd[8];
        #pragma unroll
        for (int t = 0; t < 8; ++t) {
            avs[t] = a_s[t * 16 + l16];
            avd[t] = a_d[t * 16 + l16];
        }
        #pragma unroll
        for (int r = 0; r < 4; ++r) {
            float ps = 0.f, pd = 0.f;
            #pragma unroll
            for (int t = 0; t < 8; ++t) {
                ps = fmaf(acc[t][r], avs[t], ps);
                pd = fmaf(acc[t][r], avd[t], pd);
            }
            #pragma unroll
            for (int o = 1; o < 16; o <<= 1) {
                ps += __shfl_xor(ps, o);
                pd += __shfl_xor(pd, o);
            }
            int row = orow0 + r;
            if (l16 == 0 && row < M) { as_[row] = ps; ad_[row] = pd; }
        }
    }
}

// per-dst softmax aggregation (fp8 gather, HW decode). item = 4 nodes (1/wave).
// POOL: fuse global_add_pool (LDS combine of the 4 nodes + run-length atomics).
template<bool POOL>
__device__ __forceinline__ void dev_agg_item(int it, const int* __restrict__ rowbeg,
                                             const int* __restrict__ rowend,
                                             const int* __restrict__ colidx,
                                             const u8* __restrict__ hp8,
                                             const float* __restrict__ as_,
                                             const float* __restrict__ ad_,
                                             const float* __restrict__ bl,
                                             u16* __restrict__ hout,
                                             int n, int relu,
                                             const int* __restrict__ batch,
                                             float* __restrict__ pooled) {
    int wv = threadIdx.x >> 6;
    int node = it * 4 + wv;
    int lane = threadIdx.x & 63;
    bool valid = node < n;
    int beg = 0, end = 0;
    float adi = 0.f;
    if (valid) { beg = rowbeg[node]; end = rowend[node]; adi = ad_[node]; }
    int deg = end - beg;

    // lane t owns edge t (first 64)
    int  srcl = (lane < deg) ? colidx[beg + lane] : 0;
    float el = -1e30f;
    if (lane < deg) {
        float e = as_[srcl] + adi;
        el = e > 0.f ? e : NEG * e;
    }

    float m = el;
    for (int jj = beg + 64 + lane; jj < end; jj += 64) {
        float e = as_[colidx[jj]] + adi;
        e = e > 0.f ? e : NEG * e;
        m = fmaxf(m, e);
    }
    #pragma unroll
    for (int off = 32; off; off >>= 1) m = fmaxf(m, __shfl_xor(m, off));

    float ex = (lane < deg) ? __expf(el - m) : 0.f;
    float ssum = ex;
    for (int jj = beg + 64 + lane; jj < end; jj += 64) {
        float e = as_[colidx[jj]] + adi;
        e = e > 0.f ? e : NEG * e;
        ssum += __expf(e - m);
    }
    #pragma unroll
    for (int off = 32; off; off >>= 1) ssum += __shfl_xor(ssum, off);
    float wl = ex;              // UNNORMALIZED edge weight (1/sum in epilogue)

    // ---- pass 2: half-wave per edge, fp8 row gather ----
    int hl = lane & 31;
    int half = lane >> 5;
    float a0 = 0.f, a1 = 0.f, a2 = 0.f, a3 = 0.f;
    int cnt = deg < 64 ? deg : 64;
    int npair = (cnt + 1) >> 1;

    int p = 0;
    for (; p + 4 <= npair; p += 4) {
        #pragma unroll
        for (int i = 0; i < 4; ++i) {
            int e  = 2 * (p + i) + half;
            int ec = e < cnt ? e : cnt - 1;
            int   s = __shfl(srcl, ec);
            float w = (e < cnt) ? __shfl(wl, ec) : 0.f;
            u32 v = ((const u32*)(hp8 + (size_t)s * HF))[hl];
            f32x2 lo = __builtin_amdgcn_cvt_pk_f32_fp8((int)v, false);
            f32x2 hi = __builtin_amdgcn_cvt_pk_f32_fp8((int)v, true);
            a0 = fmaf(w, lo.x, a0); a1 = fmaf(w, lo.y, a1);
            a2 = fmaf(w, hi.x, a2); a3 = fmaf(w, hi.y, a3);
        }
    }
    for (; p < npair; ++p) {
        int e  = 2 * p + half;
        int ec = e < cnt ? e : cnt - 1;
        int   s = __shfl(srcl, ec);
        float w = (e < cnt) ? __shfl(wl, ec) : 0.f;
        u32 v = ((const u32*)(hp8 + (size_t)s * HF))[hl];
        f32x2 lo = __builtin_amdgcn_cvt_pk_f32_fp8((int)v, false);
        f32x2 hi = __builtin_amdgcn_cvt_pk_f32_fp8((int)v, true);
        a0 = fmaf(w, lo.x, a0); a1 = fmaf(w, lo.y, a1);
        a2 = fmaf(w, hi.x, a2); a3 = fmaf(w, hi.y, a3);
    }
    // rare deg>64 tail: half 0 only
    for (int jj = beg + 64; jj < end; ++jj) {
        int srcn = colidx[jj];
        float e = as_[srcn] + adi;
        e = e > 0.f ? e : NEG * e;
        float w = (half == 0) ? __expf(e - m) : 0.f;
        u32 v = ((const u32*)(hp8 + (size_t)srcn * HF))[hl];
        f32x2 lo = __builtin_amdgcn_cvt_pk_f32_fp8((int)v, false);
        f32x2 hi = __builtin_amdgcn_cvt_pk_f32_fp8((int)v, true);
        a0 = fmaf(w, lo.x, a0); a1 = fmaf(w, lo.y, a1);
        a2 = fmaf(w, hi.x, a2); a3 = fmaf(w, hi.y, a3);
    }

    // combine halves
    a0 += __shfl_xor(a0, 32); a1 += __shfl_xor(a1, 32);
    a2 += __shfl_xor(a2, 32); a3 += __shfl_xor(a3, 32);

    if constexpr (!POOL) {
        if (half == 0 && valid) {
            float inv = 1.f / ssum;
            float4 bb = ((const float4*)bl)[hl];
            a0 = fmaf(a0, inv, bb.x); a1 = fmaf(a1, inv, bb.y);
            a2 = fmaf(a2, inv, bb.z); a3 = fmaf(a3, inv, bb.w);
            if (relu) {
                a0 = fmaxf(a0, 0.f); a1 = fmaxf(a1, 0.f);
                a2 = fmaxf(a2, 0.f); a3 = fmaxf(a3, 0.f);
            }
            uint2 o;
            o.x = ((u32)f2b(a1) << 16) | (u32)f2b(a0);
            o.y = ((u32)f2b(a3) << 16) | (u32)f2b(a2);
            ((uint2*)(hout + (size_t)node * HF))[hl] = o;
        }
    } else {
        // fused global_add_pool: LDS combine of the block's 4 nodes, then
        // run-length-compressed atomicAdd into pooled[batch[node]].
        __shared__ float ptile[4][HF];
        if (half == 0) {
            float o0 = 0.f, o1 = 0.f, o2 = 0.f, o3 = 0.f;
            if (valid) {
                float inv = 1.f / ssum;
                float4 bb = ((const float4*)bl)[hl];
                o0 = fmaf(a0, inv, bb.x); o1 = fmaf(a1, inv, bb.y);
                o2 = fmaf(a2, inv, bb.z); o3 = fmaf(a3, inv, bb.w);
            }
            ptile[wv][hl * 4 + 0] = o0; ptile[wv][hl * 4 + 1] = o1;
            ptile[wv][hl * 4 + 2] = o2; ptile[wv][hl * 4 + 3] = o3;
        }
        __syncthreads();
        int tid = threadIdx.x;
        if (tid < HF) {
            float acc = 0.f;
            int curb = -1;
            #pragma unroll
            for (int s2 = 0; s2 < 4; ++s2) {
                int nd = it * 4 + s2;
                if (nd < n) {
                    int b = batch[nd];
                    if (b != curb) {
                        if (curb >= 0) atomicAdd(&pooled[curb * HF + tid], acc);
                        curb = b;
                        acc = 0.f;
                    }
                    acc += ptile[s2][tid];
                }
            }
            if (curb >= 0) atomicAdd(&pooled[curb * HF + tid], acc);
        }
        __syncthreads();   // ptile safe for next grid-stride iteration
    }
}

// ======================= cooperative mega-kernel =======================
struct MegaArgs {
    const float* x; const int* esrc; const int* edst; const int* batch;
    const float* W0; const float* b0;
    const float* a_src; const float* a_dst; const float* bl;
    const float* Wf; const float* bf; float* out;
    u16* hb; u8* hp8; u16* Wp;
    float* as_; float* ad_;
    int* rowbeg; int* rowend; int* colidx; u32* epart; int* bucketCur;
    float* pooled;
    const float* Wl;
    int N, E, Et, NB, gemmb, partb;
};

__global__ __launch_bounds__(256) void k_mega(MegaArgs A) {
    cg::grid_group grid = cg::this_grid();
    const int nb = gridDim.x;

    // P0: pack weights + init buckets + zero pooled
    for (int w = blockIdx.x; w < 65; w += nb)
        dev_pack_init(w, A.W0, A.Wl, A.Wp, A.bucketCur, A.pooled);
    grid.sync();

    // P1: gemm0 (x @ W0 + b0 -> bf16 hb)  ||  bucket partition
    {
        int tot = A.gemmb + A.partb;
        for (int w = blockIdx.x; w < tot; w += nb) {
            if (w < A.gemmb)
                dev_gemm<true, false>(w, nullptr, A.x, A.Wp, A.b0,
                                      nullptr, nullptr, nullptr, nullptr, A.hb, nullptr, A.N);
            else
                dev_bpart(w - A.gemmb, A.esrc, A.edst, A.bucketCur, A.epart, A.E, A.Et);
        }
    }
    grid.sync();

    // P2: layer-0 gemm (+dots, fp8 out)  ||  bucket CSR
    {
        int tot = A.gemmb + A.NB;
        for (int w = blockIdx.x; w < tot; w += nb) {
            if (w < A.gemmb)
                dev_gemm<false, true>(w, A.hb, nullptr, A.Wp + (size_t)1 * HF * HF, nullptr,
                                      A.a_src, A.a_dst, A.as_, A.ad_, nullptr, A.hp8, A.N);
            else
                dev_bcsr(w - A.gemmb, A.epart, A.bucketCur, A.rowbeg, A.rowend, A.colidx, A.N);
        }
    }
    grid.sync();

    const int aggItems = (A.N + 3) >> 2;

    // P3: agg layer 0 (relu)
    for (int it = blockIdx.x; it < aggItems; it += nb)
        dev_agg_item<false>(it, A.rowbeg, A.rowend, A.colidx, A.hp8, A.as_, A.ad_,
                            A.bl, A.hb, A.N, 1, nullptr, nullptr);
    grid.sync();

    // P4: layer-1 gemm
    for (int w = blockIdx.x; w < A.gemmb; w += nb)
        dev_gemm<false, true>(w, A.hb, nullptr, A.Wp + (size_t)2 * HF * HF, nullptr,
                              A.a_src + HF, A.a_dst + HF, A.as_, A.ad_, nullptr, A.hp8, A.N);
    grid.sync();

    // P5: agg layer 1 (relu)
    for (int it = blockIdx.x; it < aggItems; it += nb)
        dev_agg_item<false>(it, A.rowbeg, A.rowend, A.colidx, A.hp8, A.as_, A.ad_,
                            A.bl + HF, A.hb, A.N, 1, nullptr, nullptr);
    grid.sync();

    // P6: layer-2 gemm
    for (int w = blockIdx.x; w < A.gemmb; w += nb)
        dev_gemm<false, true>(w, A.hb, nullptr, A.Wp + (size_t)3 * HF * HF, nullptr,
                              A.a_src + 2 * HF, A.a_dst + 2 * HF, A.as_, A.ad_, nullptr, A.hp8, A.N);
    grid.sync();

    // P7: agg layer 2 (no relu) + fused global_add_pool
    for (int it = blockIdx.x; it < aggItems; it += nb)
        dev_agg_item<true>(it, A.rowbeg, A.rowend, A.colidx, A.hp8, A.as_, A.ad_,
                           A.bl + 2 * HF, nullptr, A.N, 0, A.batch, A.pooled);
    grid.sync();

    // P8: final linear (64 graphs x 64 outputs)
    for (int g = blockIdx.x; g < GCOUNT; g += nb) {
        int o = threadIdx.x;
        if (o < OUTF) {
            float acc = A.bf[o];
            #pragma unroll 8
            for (int k = 0; k < HF; ++k)
                acc = fmaf(A.pooled[g * HF + k], A.Wf[k * OUTF + o], acc);
            A.out[g * OUTF + o] = acc;
        }
    }
}

// ======================= fallback multi-launch wrappers =======================
__global__ void k_pack_init(const float* __restrict__ W0, const float* __restrict__ Wl,
                            u16* __restrict__ P, int* bucketCur, float* pooled) {
    dev_pack_init(blockIdx.x, W0, Wl, P, bucketCur, pooled);
}

__global__ __launch_bounds__(256) void k_gemm0_bpart(const float* __restrict__ x,
                                                     const u16* __restrict__ Wp,
                                                     const float* __restrict__ b0,
                                                     u16* __restrict__ hb, int M, int gemmb,
                                                     const int* __restrict__ esrc,
                                                     const int* __restrict__ edst,
                                                     int* __restrict__ bucketCur,
                                                     u32* __restrict__ epart, int ne, int ntot) {
    if ((int)blockIdx.x < gemmb)
        dev_gemm<true, false>(blockIdx.x, nullptr, x, Wp, b0,
                              nullptr, nullptr, nullptr, nullptr, hb, nullptr, M);
    else
        dev_bpart(blockIdx.x - gemmb, esrc, edst, bucketCur, epart, ne, ntot);
}

__global__ __launch_bounds__(256) void k_gemm1_bcsr(const u16* __restrict__ hb,
                                                    const u16* __restrict__ Bp,
                                                    const float* __restrict__ a_s,
                                                    const float* __restrict__ a_d,
                                                    float* __restrict__ as_,
                                                    float* __restrict__ ad_,
                                                    u8* __restrict__ hp8, int M, int gemmb,
                                                    const u32* __restrict__ epart,
                                                    const int* __restrict__ bucketCur,
                                                    int* __restrict__ rowbeg,
                                                    int* __restrict__ rowend,
                                                    int* __restrict__ colidx, int n) {
    if ((int)blockIdx.x < gemmb)
        dev_gemm<false, true>(blockIdx.x, hb, nullptr, Bp, nullptr,
                              a_s, a_d, as_, ad_, nullptr, hp8, M);
    else
        dev_bcsr(blockIdx.x - gemmb, epart, bucketCur, rowbeg, rowend, colidx, n);
}

__global__ __launch_bounds__(256) void k_gemm_layer(const u16* __restrict__ hb,
                                                    const u16* __restrict__ Bp,
                                                    const float* __restrict__ a_s,
                                                    const float* __restrict__ a_d,
                                                    float* __restrict__ as_,
                                                    float* __restrict__ ad_,
                                                    u8* __restrict__ hp8, int M) {
    dev_gemm<false, true>(blockIdx.x, hb, nullptr, Bp, nullptr,
                          a_s, a_d, as_, ad_, nullptr, hp8, M);
}

__global__ __launch_bounds__(256) void k_agg(const int* __restrict__ rowbeg,
                                             const int* __restrict__ rowend,
                                             const int* __restrict__ colidx,
                                             const u8* __restrict__ hp8,
                                             const float* __restrict__ as_,
                                             const float* __restrict__ ad_,
                                             const float* __restrict__ bl,
                                             u16* __restrict__ hout,
                                             int n, int relu) {
    dev_agg_item<false>(blockIdx.x, rowbeg, rowend, colidx, hp8, as_, ad_, bl,
                        hout, n, relu, nullptr, nullptr);
}

__global__ __launch_bounds__(128) void k_pool(const u16* __restrict__ hb,
                                              const int* __restrict__ batch,
                                              float* __restrict__ pooled, int n) {
    int r0 = blockIdx.x * PROWS;
    int r1 = min(r0 + PROWS, n);
    if (r0 >= r1) return;
    int t = threadIdx.x;
    int cur = batch[r0];
    float acc = 0.f;
    for (int i = r0; i < r1; ++i) {
        int b = batch[i];
        if (b != cur) {
            atomicAdd(&pooled[cur * HF + t], acc);
            acc = 0.f;
            cur = b;
        }
        acc += __builtin_bit_cast(float, (u32)hb[(size_t)i * HF + t] << 16);
    }
    atomicAdd(&pooled[cur * HF + t], acc);
}

__global__ void k_final(const float* __restrict__ pooled, const float* __restrict__ Wf,
                        const float* __restrict__ bf, float* __restrict__ out) {
    int g = blockIdx.x, o = threadIdx.x;   // 64 threads
    float acc = bf[o];
    #pragma unroll 8
    for (int k = 0; k < HF; ++k) acc = fmaf(pooled[g * HF + k], Wf[k * OUTF + o], acc);
    out[g * OUTF + o] = acc;
}

// ======================= launch =======================
extern "C" void kernel_launch(void* const* d_in, const int* in_sizes, int n_in,
                              void* d_out, int out_size, void* d_ws, size_t ws_size,
                              hipStream_t stream) {
    const float* x      = (const float*)d_in[0];
    const int*   edge   = (const int*)d_in[1];
    const int*   batch  = (const int*)d_in[2];
    const float* W0     = (const float*)d_in[3];
    const float* b0     = (const float*)d_in[4];
    const float* Wl     = (const float*)d_in[5];
    const float* a_src  = (const float*)d_in[6];
    const float* a_dst  = (const float*)d_in[7];
    const float* bl     = (const float*)d_in[8];
    const float* Wf     = (const float*)d_in[9];
    const float* bf     = (const float*)d_in[10];
    float* out = (float*)d_out;

    const int N  = in_sizes[2];
    const int E  = in_sizes[1] / 2;
    const int Et = E + N;
    const int L  = 3;
    const int NB = (N + 255) >> 8;               // buckets (<= 256)

    char* ws = (char*)d_ws;
    size_t off = 0;
    auto alloc = [&](size_t bytes) { char* p = ws + off; off += (bytes + 255) & ~(size_t)255; return p; };
    u16*   hb      = (u16*)alloc((size_t)N * HF * 2);
    u8*    hp8     = (u8*)alloc((size_t)N * HF);
    u16*   Wp      = (u16*)alloc((size_t)4 * HF * HF * 2);
    float* as_     = (float*)alloc((size_t)N * 4);
    float* ad_     = (float*)alloc((size_t)N * 4);
    int*   rowbeg  = (int*)alloc((size_t)N * 4);
    int*   rowend  = (int*)alloc((size_t)N * 4);
    int*   colidx  = (int*)alloc((size_t)NB * BCAP * 4);
    u32*   epart   = (u32*)alloc((size_t)NB * BCAP * 4);
    int*   bucketCur = (int*)alloc(256 * 4);
    float* pooled  = (float*)alloc((size_t)GCOUNT * HF * 4);
    (void)ws_size; (void)n_in; (void)out_size;

    const int wb4   = (N + 3) / 4;
    const int gemmb = (N + 63) / 64;
    const int partb = (Et + CH - 1) / CH;

    const int* esrc = edge;
    const int* edst = edge + E;

    // --- cooperative mega-kernel path (grid sized to exact co-residency) ---
    static int g_grid = -2;
    if (g_grid == -2) {
        int dev = 0;
        (void)hipGetDevice(&dev);
        int nCU = 0;
        (void)hipDeviceGetAttribute(&nCU, hipDeviceAttributeMultiprocessorCount, dev);
        int perCU = 0;
        hipError_t e = hipOccupancyMaxActiveBlocksPerMultiprocessor(&perCU, k_mega, 256, 0);
        g_grid = (e == hipSuccess && perCU > 0 && nCU > 0) ? perCU * nCU : -1;
    }

    if (g_grid > 0) {
        MegaArgs ha;
        ha.x = x; ha.esrc = esrc; ha.edst = edst; ha.batch = batch;
        ha.W0 = W0; ha.b0 = b0; ha.a_src = a_src; ha.a_dst = a_dst; ha.bl = bl;
        ha.Wf = Wf; ha.bf = bf; ha.out = out;
        ha.hb = hb; ha.hp8 = hp8; ha.Wp = Wp;
        ha.as_ = as_; ha.ad_ = ad_;
        ha.rowbeg = rowbeg; ha.rowend = rowend; ha.colidx = colidx;
        ha.epart = epart; ha.bucketCur = bucketCur; ha.pooled = pooled;
        ha.Wl = Wl;
        ha.N = N; ha.E = E; ha.Et = Et; ha.NB = NB; ha.gemmb = gemmb; ha.partb = partb;
        void* kargs[] = { (void*)&ha };
        hipError_t err = hipLaunchCooperativeKernel((void*)k_mega, dim3(g_grid), dim3(256),
                                                    kargs, 0, stream);
        if (err == hipSuccess) return;
        g_grid = -1;   // cooperative path unavailable -> fall through
    }

    // --- fallback: proven multi-launch path ---
    k_pack_init<<<65, 256, 0, stream>>>(W0, Wl, Wp, bucketCur, pooled);
    k_gemm0_bpart<<<gemmb + partb, 256, 0, stream>>>(x, Wp, b0, hb, N, gemmb,
                                                     esrc, edst, bucketCur, epart, E, Et);
    k_gemm1_bcsr<<<gemmb + NB, 256, 0, stream>>>(hb, Wp + (size_t)1 * HF * HF,
                                                 a_src, a_dst, as_, ad_, hp8, N, gemmb,
                                                 epart, bucketCur, rowbeg, rowend, colidx, N);
    for (int l = 0; l < L; ++l) {
        if (l > 0)
            k_gemm_layer<<<gemmb, 256, 0, stream>>>(hb, Wp + (size_t)(l + 1) * HF * HF,
                                                    a_src + l * HF, a_dst + l * HF,
                                                    as_, ad_, hp8, N);
        k_agg<<<wb4, 256, 0, stream>>>(rowbeg, rowend, colidx, hp8, as_, ad_, bl + l * HF, hb, N,
                                       (l < L - 1) ? 1 : 0);
    }
    k_pool<<<(N + PROWS - 1) / PROWS, 128, 0, stream>>>(hb, batch, pooled, N);
    k_final<<<GCOUNT, OUTF, 0, stream>>>(pooled, Wf, bf, out);
}

// Round 3
// 266.339 us; speedup vs baseline: 3.3621x; 3.3621x over previous
//
#include <hip/hip_runtime.h>
#include <hip/hip_bf16.h>
#include <math.h>

#define HF 128          // hidden / input feature dim
#define GCOUNT 64       // graphs in batch
#define OUTF 64         // final output features
#define NEG 0.2f        // leaky relu slope
#define CH 2048         // edges per partition block
#define BCAP 8192       // per-bucket edge capacity (expected ~4340, +50 sigma)

typedef unsigned short u16;
typedef unsigned int   u32;
typedef unsigned char  u8;
typedef short bf16x8 __attribute__((ext_vector_type(8)));
typedef float f32x4  __attribute__((ext_vector_type(4)));
typedef float f32x2  __attribute__((ext_vector_type(2)));

// fp32 -> bf16 (RNE) bit trick
__device__ __forceinline__ u16 f2b(float f) {
    u32 u = __builtin_bit_cast(u32, f);
    u32 r = (u + 0x7FFFu + ((u >> 16) & 1u)) >> 16;
    return (u16)r;
}

// ---- hardware fp8 e4m3fn codec (gfx950 OCP; v_cvt_pk_* — 2 elems/inst) ----
__device__ __forceinline__ u8 f2q(float f) {
    return (u8)(__builtin_amdgcn_cvt_pk_fp8_f32(f, f, 0, false) & 0xFF);
}

// ======================= fused pack + init =======================
// blocks 0..31: pack 4 weight matrices into MFMA B-frag order
//   P[m][(t*4+kc)*64+lane][j] = bf16(W_m[kc*32+quad*8+j][16t+(lane&15)])
// block 32: init bucketCur; blocks 33..64: zero pooled
__global__ void k_pack_init(const float* __restrict__ W0, const float* __restrict__ Wl,
                            u16* __restrict__ P, int* bucketCur, float* pooled) {
    if (blockIdx.x < 32) {
        int m = blockIdx.x >> 3;                       // 0..3: W0, Wl[0..2]
        int i = (blockIdx.x & 7) * 256 + threadIdx.x;  // 0..2047
        const float* W = (m == 0) ? W0 : Wl + (size_t)(m - 1) * HF * HF;
        u16* Pm = P + (size_t)m * HF * HF;
        int lane = i & 63, kc = (i >> 6) & 3, t = i >> 8;
        int quad = lane >> 4, col = 16 * t + (lane & 15);
        #pragma unroll
        for (int j = 0; j < 8; ++j) {
            int k = kc * 32 + quad * 8 + j;
            Pm[(size_t)i * 8 + j] = f2b(W[k * HF + col]);
        }
    } else if (blockIdx.x == 32) {
        bucketCur[threadIdx.x] = threadIdx.x * BCAP;
    } else {
        pooled[(blockIdx.x - 33) * 256 + threadIdx.x] = 0.f;
    }
}

// ======================= bucketed CSR build (device fns, fixed-capacity buckets) ==========
// bucket b = dst >> 8; bucket region = [b*BCAP, b*BCAP + cnt_b).

// single pass: LDS hist -> chunk reservation -> packed scatter (src<<8 | dst&255)
// edge (s,d) register-cached across the two passes (fully unrolled, static idx)
__device__ __forceinline__ void dev_bpart(int bx, const int* __restrict__ esrc,
                                          const int* __restrict__ edst,
                                          int* __restrict__ bucketCur,
                                          u32* __restrict__ epart, int ne, int ntot) {
    __shared__ int cnt[256];
    __shared__ int base[256];
    int tid = threadIdx.x;
    int t0 = bx * CH, t1 = min(t0 + CH, ntot);
    cnt[tid] = 0;
    __syncthreads();
    int sreg[8], dreg[8];
    #pragma unroll
    for (int it = 0; it < 8; ++it) {
        int t = t0 + tid + it * 256;
        int s = 0, d = -1;
        if (t < t1) {
            if (t < ne) { s = esrc[t]; d = edst[t]; }
            else        { s = t - ne; d = s; }
            atomicAdd(&cnt[d >> 8], 1);
        }
        sreg[it] = s; dreg[it] = d;
    }
    __syncthreads();
    int c = cnt[tid];
    base[tid] = c ? atomicAdd(&bucketCur[tid], c) : 0;
    cnt[tid] = 0;
    __syncthreads();
    #pragma unroll
    for (int it = 0; it < 8; ++it) {
        int d = dreg[it];
        if (d >= 0) {
            int b = d >> 8;
            int pos = base[b] + atomicAdd(&cnt[b], 1);
            epart[pos] = ((u32)sreg[it] << 8) | (u32)(d & 255);
        }
    }
}

// one block per bucket: local degree hist + scan -> rowbeg/rowend + colidx scatter
__device__ __forceinline__ void dev_bcsr(int bx, const u32* __restrict__ epart,
                                         const int* __restrict__ bucketCur,
                                         int* __restrict__ rowbeg,
                                         int* __restrict__ rowend,
                                         int* __restrict__ colidx, int n) {
    __shared__ int deg[256], offs[256], curs[256], s[256];
    int b = bx, tid = threadIdx.x;
    int e0 = b * BCAP, e1 = bucketCur[b];
    deg[tid] = 0;
    curs[tid] = 0;
    __syncthreads();
    for (int t = e0 + tid; t < e1; t += 256)
        atomicAdd(&deg[epart[t] & 255u], 1);
    __syncthreads();
    int v = deg[tid];
    s[tid] = v;
    __syncthreads();
    int acc = v;
    for (int off = 1; off < 256; off <<= 1) {
        int t = (tid >= off) ? s[tid - off] : 0;
        __syncthreads();
        acc += t;
        s[tid] = acc;
        __syncthreads();
    }
    int excl = acc - v;
    offs[tid] = excl;
    int node = (b << 8) + tid;
    if (node < n) {
        rowbeg[node] = e0 + excl;
        rowend[node] = e0 + excl + v;
    }
    __syncthreads();
    for (int t = e0 + tid; t < e1; t += 256) {
        u32 e = epart[t];
        int l = e & 255u;
        int pos = e0 + offs[l] + atomicAdd(&curs[l], 1);
        colidx[pos] = (int)(e >> 8);
    }
}

// ======================= MFMA GEMM (+bias, + optional fused alpha dots) ==========
// block = 256 (4 waves); wave w owns rows m0+16w..+15, all 128 cols (8 n-tiles).
// C/D layout: col = lane&15 (in tile), row = quad*4 + reg
// Q8: write fp8 output (layer hp); else bf16 output.
template<bool A32, bool Q8>
__device__ __forceinline__ void dev_gemm(int bx, const u16* __restrict__ Ab,
                                         const float* __restrict__ Af,
                                         const u16* __restrict__ Bp,
                                         const float* __restrict__ bias,
                                         const float* __restrict__ a_s,
                                         const float* __restrict__ a_d,
                                         float* __restrict__ as_,
                                         float* __restrict__ ad_,
                                         u16* __restrict__ C,
                                         u8* __restrict__ C8, int M) {
    int lane = threadIdx.x & 63;
    int wave = threadIdx.x >> 6;
    int quad = lane >> 4, l16 = lane & 15;
    int m0 = bx * 64 + wave * 16;
    int arow = m0 + l16;
    bool aval = arow < M;
    const bf16x8* Av = A32 ? nullptr : (const bf16x8*)(Ab + (size_t)arow * HF);
    const bf16x8* Bv = (const bf16x8*)Bp;
    f32x4 acc[8] = {};

    #pragma unroll
    for (int kc = 0; kc < 4; ++kc) {
        bf16x8 a = {};
        if (aval) {
            if constexpr (A32) {
                const float* ap = Af + (size_t)arow * HF + kc * 32 + quad * 8;
                float4 f0 = *(const float4*)ap;
                float4 f1 = *(const float4*)(ap + 4);
                a[0] = (short)f2b(f0.x); a[1] = (short)f2b(f0.y);
                a[2] = (short)f2b(f0.z); a[3] = (short)f2b(f0.w);
                a[4] = (short)f2b(f1.x); a[5] = (short)f2b(f1.y);
                a[6] = (short)f2b(f1.z); a[7] = (short)f2b(f1.w);
            } else {
                a = Av[kc * 4 + quad];
            }
        }
        #pragma unroll
        for (int t = 0; t < 8; ++t)
            acc[t] = __builtin_amdgcn_mfma_f32_16x16x32_bf16(a, Bv[t * 256 + kc * 64 + lane],
                                                             acc[t], 0, 0, 0);
    }

    int orow0 = m0 + quad * 4;
    #pragma unroll
    for (int t = 0; t < 8; ++t) {
        float b4 = bias ? bias[t * 16 + l16] : 0.f;
        #pragma unroll
        for (int r = 0; r < 4; ++r) {
            int orow = orow0 + r;
            if (orow < M) {
                float v = acc[t][r] + b4;
                if constexpr (Q8) C8[(size_t)orow * HF + t * 16 + l16] = f2q(v);
                else              C [(size_t)orow * HF + t * 16 + l16] = f2b(v);
            }
        }
    }

    // fused attention dots (fp32 accumulators -> exact attention weights)
    if (as_) {
        float avs[8], avd[8];
        #pragma unroll
        for (int t = 0; t < 8; ++t) {
            avs[t] = a_s[t * 16 + l16];
            avd[t] = a_d[t * 16 + l16];
        }
        #pragma unroll
        for (int r = 0; r < 4; ++r) {
            float ps = 0.f, pd = 0.f;
            #pragma unroll
            for (int t = 0; t < 8; ++t) {
                ps = fmaf(acc[t][r], avs[t], ps);
                pd = fmaf(acc[t][r], avd[t], pd);
            }
            #pragma unroll
            for (int o = 1; o < 16; o <<= 1) {
                ps += __shfl_xor(ps, o);
                pd += __shfl_xor(pd, o);
            }
            int row = orow0 + r;
            if (l16 == 0 && row < M) { as_[row] = ps; ad_[row] = pd; }
        }
    }
}

// ---- merged dispatch 1: gemm0 (x @ W0 + b0 -> bf16 hb)  ||  bucket partition ----
__global__ __launch_bounds__(256) void k_gemm0_bpart(const float* __restrict__ x,
                                                     const u16* __restrict__ Wp,
                                                     const float* __restrict__ b0,
                                                     u16* __restrict__ hb, int M, int gemmb,
                                                     const int* __restrict__ esrc,
                                                     const int* __restrict__ edst,
                                                     int* __restrict__ bucketCur,
                                                     u32* __restrict__ epart, int ne, int ntot) {
    if ((int)blockIdx.x < gemmb)
        dev_gemm<true, false>(blockIdx.x, nullptr, x, Wp, b0,
                              nullptr, nullptr, nullptr, nullptr, hb, nullptr, M);
    else
        dev_bpart(blockIdx.x - gemmb, esrc, edst, bucketCur, epart, ne, ntot);
}

// ---- merged dispatch 2: layer-1 gemm (hb @ Wl0 -> fp8 hp + alpha dots)  ||  bucket CSR ----
__global__ __launch_bounds__(256) void k_gemm1_bcsr(const u16* __restrict__ hb,
                                                    const u16* __restrict__ Bp,
                                                    const float* __restrict__ a_s,
                                                    const float* __restrict__ a_d,
                                                    float* __restrict__ as_,
                                                    float* __restrict__ ad_,
                                                    u8* __restrict__ hp8, int M, int gemmb,
                                                    const u32* __restrict__ epart,
                                                    const int* __restrict__ bucketCur,
                                                    int* __restrict__ rowbeg,
                                                    int* __restrict__ rowend,
                                                    int* __restrict__ colidx, int n) {
    if ((int)blockIdx.x < gemmb)
        dev_gemm<false, true>(blockIdx.x, hb, nullptr, Bp, nullptr,
                              a_s, a_d, as_, ad_, nullptr, hp8, M);
    else
        dev_bcsr(blockIdx.x - gemmb, epart, bucketCur, rowbeg, rowend, colidx, n);
}

// ---- standalone layer gemm (layers 2..L) ----
__global__ __launch_bounds__(256) void k_gemm_layer(const u16* __restrict__ hb,
                                                    const u16* __restrict__ Bp,
                                                    const float* __restrict__ a_s,
                                                    const float* __restrict__ a_d,
                                                    float* __restrict__ as_,
                                                    float* __restrict__ ad_,
                                                    u8* __restrict__ hp8, int M) {
    dev_gemm<false, true>(blockIdx.x, hb, nullptr, Bp, nullptr,
                          a_s, a_d, as_, ad_, nullptr, hp8, M);
}

// ======================= per-dst softmax aggregation (fp8 gather, HW decode) ==========
// One wave per node (4 nodes/block). Pass 2: half-wave per edge (32 lanes x 4B =
// one 128B fp8 row), 2 edges per load group, unroll x4. HW fp8 decode.
// Weights accumulated UNNORMALIZED; 1/sum applied once in the epilogue.
// POOL: fuse global_add_pool — LDS combine of the block's 4 node rows, then
// run-length-compressed atomicAdd into pooled[batch[node]] (verified in R2 mega).
template<bool POOL>
__device__ __forceinline__ void dev_agg_item(int it, const int* __restrict__ rowbeg,
                                             const int* __restrict__ rowend,
                                             const int* __restrict__ colidx,
                                             const u8* __restrict__ hp8,
                                             const float* __restrict__ as_,
                                             const float* __restrict__ ad_,
                                             const float* __restrict__ bl,
                                             u16* __restrict__ hout,
                                             int n, int relu,
                                             const int* __restrict__ batch,
                                             float* __restrict__ pooled) {
    int wv = threadIdx.x >> 6;
    int node = it * 4 + wv;
    int lane = threadIdx.x & 63;
    bool valid = node < n;
    int beg = 0, end = 0;
    float adi = 0.f;
    if (valid) { beg = rowbeg[node]; end = rowend[node]; adi = ad_[node]; }
    int deg = end - beg;

    // lane t owns edge t (first 64)
    int  srcl = (lane < deg) ? colidx[beg + lane] : 0;
    float el = -1e30f;
    if (lane < deg) {
        float e = as_[srcl] + adi;
        el = e > 0.f ? e : NEG * e;
    }

    float m = el;
    for (int jj = beg + 64 + lane; jj < end; jj += 64) {
        float e = as_[colidx[jj]] + adi;
        e = e > 0.f ? e : NEG * e;
        m = fmaxf(m, e);
    }
    #pragma unroll
    for (int off = 32; off; off >>= 1) m = fmaxf(m, __shfl_xor(m, off));

    float ex = (lane < deg) ? __expf(el - m) : 0.f;
    float ssum = ex;
    for (int jj = beg + 64 + lane; jj < end; jj += 64) {
        float e = as_[colidx[jj]] + adi;
        e = e > 0.f ? e : NEG * e;
        ssum += __expf(e - m);
    }
    #pragma unroll
    for (int off = 32; off; off >>= 1) ssum += __shfl_xor(ssum, off);
    float wl = ex;              // UNNORMALIZED edge weight (1/sum in epilogue)

    // ---- pass 2: half-wave per edge, fp8 row gather ----
    int hl = lane & 31;
    int half = lane >> 5;
    float a0 = 0.f, a1 = 0.f, a2 = 0.f, a3 = 0.f;
    int cnt = deg < 64 ? deg : 64;
    int npair = (cnt + 1) >> 1;

    int p = 0;
    for (; p + 4 <= npair; p += 4) {
        #pragma unroll
        for (int i = 0; i < 4; ++i) {
            int e  = 2 * (p + i) + half;
            int ec = e < cnt ? e : cnt - 1;
            int   s = __shfl(srcl, ec);
            float w = (e < cnt) ? __shfl(wl, ec) : 0.f;
            u32 v = ((const u32*)(hp8 + (size_t)s * HF))[hl];
            f32x2 lo = __builtin_amdgcn_cvt_pk_f32_fp8((int)v, false);
            f32x2 hi = __builtin_amdgcn_cvt_pk_f32_fp8((int)v, true);
            a0 = fmaf(w, lo.x, a0); a1 = fmaf(w, lo.y, a1);
            a2 = fmaf(w, hi.x, a2); a3 = fmaf(w, hi.y, a3);
        }
    }
    for (; p < npair; ++p) {
        int e  = 2 * p + half;
        int ec = e < cnt ? e : cnt - 1;
        int   s = __shfl(srcl, ec);
        float w = (e < cnt) ? __shfl(wl, ec) : 0.f;
        u32 v = ((const u32*)(hp8 + (size_t)s * HF))[hl];
        f32x2 lo = __builtin_amdgcn_cvt_pk_f32_fp8((int)v, false);
        f32x2 hi = __builtin_amdgcn_cvt_pk_f32_fp8((int)v, true);
        a0 = fmaf(w, lo.x, a0); a1 = fmaf(w, lo.y, a1);
        a2 = fmaf(w, hi.x, a2); a3 = fmaf(w, hi.y, a3);
    }
    // rare deg>64 tail: half 0 only (avoids double count after combine)
    for (int jj = beg + 64; jj < end; ++jj) {
        int srcn = colidx[jj];
        float e = as_[srcn] + adi;
        e = e > 0.f ? e : NEG * e;
        float w = (half == 0) ? __expf(e - m) : 0.f;
        u32 v = ((const u32*)(hp8 + (size_t)srcn * HF))[hl];
        f32x2 lo = __builtin_amdgcn_cvt_pk_f32_fp8((int)v, false);
        f32x2 hi = __builtin_amdgcn_cvt_pk_f32_fp8((int)v, true);
        a0 = fmaf(w, lo.x, a0); a1 = fmaf(w, lo.y, a1);
        a2 = fmaf(w, hi.x, a2); a3 = fmaf(w, hi.y, a3);
    }

    // combine halves
    a0 += __shfl_xor(a0, 32); a1 += __shfl_xor(a1, 32);
    a2 += __shfl_xor(a2, 32); a3 += __shfl_xor(a3, 32);

    if constexpr (!POOL) {
        if (half == 0 && valid) {
            float inv = 1.f / ssum;
            float4 bb = ((const float4*)bl)[hl];
            a0 = fmaf(a0, inv, bb.x); a1 = fmaf(a1, inv, bb.y);
            a2 = fmaf(a2, inv, bb.z); a3 = fmaf(a3, inv, bb.w);
            if (relu) {
                a0 = fmaxf(a0, 0.f); a1 = fmaxf(a1, 0.f);
                a2 = fmaxf(a2, 0.f); a3 = fmaxf(a3, 0.f);
            }
            uint2 o;
            o.x = ((u32)f2b(a1) << 16) | (u32)f2b(a0);
            o.y = ((u32)f2b(a3) << 16) | (u32)f2b(a2);
            ((uint2*)(hout + (size_t)node * HF))[hl] = o;
        }
    } else {
        __shared__ float ptile[4][HF];
        if (half == 0) {
            float o0 = 0.f, o1 = 0.f, o2 = 0.f, o3 = 0.f;
            if (valid) {
                float inv = 1.f / ssum;
                float4 bb = ((const float4*)bl)[hl];
                o0 = fmaf(a0, inv, bb.x); o1 = fmaf(a1, inv, bb.y);
                o2 = fmaf(a2, inv, bb.z); o3 = fmaf(a3, inv, bb.w);
            }
            ptile[wv][hl * 4 + 0] = o0; ptile[wv][hl * 4 + 1] = o1;
            ptile[wv][hl * 4 + 2] = o2; ptile[wv][hl * 4 + 3] = o3;
        }
        __syncthreads();
        int tid = threadIdx.x;
        if (tid < HF) {
            float acc = 0.f;
            int curb = -1;
            #pragma unroll
            for (int s2 = 0; s2 < 4; ++s2) {
                int nd = it * 4 + s2;
                if (nd < n) {
                    int b = batch[nd];
                    if (b != curb) {
                        if (curb >= 0) atomicAdd(&pooled[curb * HF + tid], acc);
                        curb = b;
                        acc = 0.f;
                    }
                    acc += ptile[s2][tid];
                }
            }
            if (curb >= 0) atomicAdd(&pooled[curb * HF + tid], acc);
        }
    }
}

__global__ __launch_bounds__(256) void k_agg(const int* __restrict__ rowbeg,
                                             const int* __restrict__ rowend,
                                             const int* __restrict__ colidx,
                                             const u8* __restrict__ hp8,
                                             const float* __restrict__ as_,
                                             const float* __restrict__ ad_,
                                             const float* __restrict__ bl,
                                             u16* __restrict__ hout,
                                             int n, int relu) {
    dev_agg_item<false>(blockIdx.x, rowbeg, rowend, colidx, hp8, as_, ad_, bl,
                        hout, n, relu, nullptr, nullptr);
}

// final layer: agg (no relu) + fused global_add_pool
__global__ __launch_bounds__(256) void k_agg_pool(const int* __restrict__ rowbeg,
                                                  const int* __restrict__ rowend,
                                                  const int* __restrict__ colidx,
                                                  const u8* __restrict__ hp8,
                                                  const float* __restrict__ as_,
                                                  const float* __restrict__ ad_,
                                                  const float* __restrict__ bl,
                                                  int n,
                                                  const int* __restrict__ batch,
                                                  float* __restrict__ pooled) {
    dev_agg_item<true>(blockIdx.x, rowbeg, rowend, colidx, hp8, as_, ad_, bl,
                       nullptr, n, 0, batch, pooled);
}

__global__ void k_final(const float* __restrict__ pooled, const float* __restrict__ Wf,
                        const float* __restrict__ bf, float* __restrict__ out) {
    int g = blockIdx.x, o = threadIdx.x;   // 64 threads
    float acc = bf[o];
    #pragma unroll 8
    for (int k = 0; k < HF; ++k) acc = fmaf(pooled[g * HF + k], Wf[k * OUTF + o], acc);
    out[g * OUTF + o] = acc;
}

// ======================= launch =======================
extern "C" void kernel_launch(void* const* d_in, const int* in_sizes, int n_in,
                              void* d_out, int out_size, void* d_ws, size_t ws_size,
                              hipStream_t stream) {
    const float* x      = (const float*)d_in[0];
    const int*   edge   = (const int*)d_in[1];
    const int*   batch  = (const int*)d_in[2];
    const float* W0     = (const float*)d_in[3];
    const float* b0     = (const float*)d_in[4];
    const float* Wl     = (const float*)d_in[5];
    const float* a_src  = (const float*)d_in[6];
    const float* a_dst  = (const float*)d_in[7];
    const float* bl     = (const float*)d_in[8];
    const float* Wf     = (const float*)d_in[9];
    const float* bf     = (const float*)d_in[10];
    float* out = (float*)d_out;

    const int N  = in_sizes[2];
    const int E  = in_sizes[1] / 2;
    const int Et = E + N;
    const int L  = 3;
    const int NB = (N + 255) >> 8;               // buckets (<= 256)

    char* ws = (char*)d_ws;
    size_t off = 0;
    auto alloc = [&](size_t bytes) { char* p = ws + off; off += (bytes + 255) & ~(size_t)255; return p; };
    u16*   hb      = (u16*)alloc((size_t)N * HF * 2);
    u8*    hp8     = (u8*)alloc((size_t)N * HF);
    u16*   Wp      = (u16*)alloc((size_t)4 * HF * HF * 2);
    float* as_     = (float*)alloc((size_t)N * 4);
    float* ad_     = (float*)alloc((size_t)N * 4);
    int*   rowbeg  = (int*)alloc((size_t)N * 4);
    int*   rowend  = (int*)alloc((size_t)N * 4);
    int*   colidx  = (int*)alloc((size_t)NB * BCAP * 4);
    u32*   epart   = (u32*)alloc((size_t)NB * BCAP * 4);
    int*   bucketCur = (int*)alloc(256 * 4);
    float* pooled  = (float*)alloc((size_t)GCOUNT * HF * 4);
    (void)ws_size; (void)n_in; (void)out_size;

    const int wb4   = (N + 3) / 4;               // wave-per-node kernels
    const int gemmb = (N + 63) / 64;
    const int partb = (Et + CH - 1) / CH;

    const int* esrc = edge;
    const int* edst = edge + E;

    // --- pack weights + init bucketCur + zero pooled (one launch) ---
    k_pack_init<<<65, 256, 0, stream>>>(W0, Wl, Wp, bucketCur, pooled);

    // --- gemm0 (x @ W0 + b0)  ||  bucket partition (independent stages) ---
    k_gemm0_bpart<<<gemmb + partb, 256, 0, stream>>>(x, Wp, b0, hb, N, gemmb,
                                                     esrc, edst, bucketCur, epart, E, Et);

    // --- layer-1 gemm (+alpha dots, fp8 out)  ||  bucket CSR (independent stages) ---
    k_gemm1_bcsr<<<gemmb + NB, 256, 0, stream>>>(hb, Wp + (size_t)1 * HF * HF,
                                                 a_src, a_dst, as_, ad_, hp8, N, gemmb,
                                                 epart, bucketCur, rowbeg, rowend, colidx, N);

    // --- GAT layers; final layer fuses global_add_pool ---
    for (int l = 0; l < L; ++l) {
        if (l > 0)
            k_gemm_layer<<<gemmb, 256, 0, stream>>>(hb, Wp + (size_t)(l + 1) * HF * HF,
                                                    a_src + l * HF, a_dst + l * HF,
                                                    as_, ad_, hp8, N);
        if (l < L - 1)
            k_agg<<<wb4, 256, 0, stream>>>(rowbeg, rowend, colidx, hp8, as_, ad_,
                                           bl + l * HF, hb, N, 1);
        else
            k_agg_pool<<<wb4, 256, 0, stream>>>(rowbeg, rowend, colidx, hp8, as_, ad_,
                                                bl + l * HF, N, batch, pooled);
    }

    // --- final linear ---
    k_final<<<GCOUNT, OUTF, 0, stream>>>(pooled, Wf, bf, out);
}